// Round 5
// baseline (216.273 us; speedup 1.0000x reference)
//
#include <hip/hip_runtime.h>
#include <math.h>

#define BOS_TAG 62
#define EOS_TAG 63
#define LTAGS   64
#define S_LEN   1024
#define CHUNK   128
#define NCHUNK  8          // S_LEN / CHUNK
#define NSLOT   15         // 8 fwd + 7 bwd chunk-runs per batch
#define LN2F    0.69314718055994530942f

#if defined(__has_builtin)
#if __has_builtin(__builtin_amdgcn_fdot2)
#define USE_FDOT2 1
#endif
#endif
#ifndef USE_FDOT2
#define USE_FDOT2 0
#endif

typedef __fp16 half2_t __attribute__((ext_vector_type(2)));

template <int CTRL>
__device__ __forceinline__ int dpp_mov(int v) {
  return __builtin_amdgcn_update_dpp(v, v, CTRL, 0xf, 0xf, false);
}
template <int CTRL>
__device__ __forceinline__ float dpp_fmax_step(float v) {
  return fmaxf(v, __int_as_float(dpp_mov<CTRL>(__float_as_int(v))));
}
// Exact wave-wide max, broadcast to all lanes (VALU DPP tree + readlane->SGPR).
__device__ __forceinline__ float wave_fmax_all(float v) {
  v = dpp_fmax_step<0x111>(v); // row_shr:1
  v = dpp_fmax_step<0x112>(v); // row_shr:2
  v = dpp_fmax_step<0x114>(v); // row_shr:4
  v = dpp_fmax_step<0x118>(v); // row_shr:8
  v = dpp_fmax_step<0x142>(v); // row_bcast15
  v = dpp_fmax_step<0x143>(v); // row_bcast31
  return __int_as_float(__builtin_amdgcn_readlane(__float_as_int(v), 63));
}
__device__ __forceinline__ float wave_sum(float v) {
#pragma unroll
  for (int off = 32; off; off >>= 1) v += __shfl_xor(v, off, 64);
  return v;
}

// ---- 64-wide broadcast dot: s_lane = sum_i x_i * P.v[i] -----------------
#if USE_FDOT2
struct PMat { half2_t v[32]; };
__device__ __forceinline__ void pmat_set(PMat& P, int i, float q0, float q1) {
  half2_t h; h[0] = (__fp16)q0; h[1] = (__fp16)q1;
  P.v[i] = h;
}
__device__ __forceinline__ float dot64(const PMat& P, float x) {
  // pack (x_j, x_{j^1}) so even lanes hold consecutive pairs
  int xo = dpp_mov<0xB1>(__float_as_int(x)); // quad_perm [1,0,3,2]
  half2_t xp = __builtin_amdgcn_cvt_pkrtz(x, __int_as_float(xo));
  int xpi = __builtin_bit_cast(int, xp);
  float a0 = 0.f, a1 = 0.f, a2 = 0.f, a3 = 0.f;
#pragma unroll
  for (int i = 0; i < 32; i += 4) {
    int s0 = __builtin_amdgcn_readlane(xpi, 2 * (i + 0));
    int s1 = __builtin_amdgcn_readlane(xpi, 2 * (i + 1));
    int s2 = __builtin_amdgcn_readlane(xpi, 2 * (i + 2));
    int s3 = __builtin_amdgcn_readlane(xpi, 2 * (i + 3));
    a0 = __builtin_amdgcn_fdot2(P.v[i + 0], __builtin_bit_cast(half2_t, s0), a0, false);
    a1 = __builtin_amdgcn_fdot2(P.v[i + 1], __builtin_bit_cast(half2_t, s1), a1, false);
    a2 = __builtin_amdgcn_fdot2(P.v[i + 2], __builtin_bit_cast(half2_t, s2), a2, false);
    a3 = __builtin_amdgcn_fdot2(P.v[i + 3], __builtin_bit_cast(half2_t, s3), a3, false);
  }
  return (a0 + a1) + (a2 + a3);
}
#else
struct PMat { float v[LTAGS]; };
__device__ __forceinline__ void pmat_set(PMat& P, int i, float q0, float q1) {
  P.v[2 * i] = q0; P.v[2 * i + 1] = q1;
}
__device__ __forceinline__ float dot64(const PMat& P, float x) {
  int xi = __float_as_int(x);
  float a0 = 0.f, a1 = 0.f, a2 = 0.f, a3 = 0.f;
#pragma unroll
  for (int i = 0; i < LTAGS; i += 4) {
    a0 = fmaf(__int_as_float(__builtin_amdgcn_readlane(xi, i + 0)), P.v[i + 0], a0);
    a1 = fmaf(__int_as_float(__builtin_amdgcn_readlane(xi, i + 1)), P.v[i + 1], a1);
    a2 = fmaf(__int_as_float(__builtin_amdgcn_readlane(xi, i + 2)), P.v[i + 2], a2);
    a3 = fmaf(__int_as_float(__builtin_amdgcn_readlane(xi, i + 3)), P.v[i + 3], a3);
  }
  return (a0 + a1) + (a2 + a3);
}
#endif

// exponent-only renorm: v *= 2^{-e}, sigma += e + 6 (the +6 re-applies the
// 1/64 folded into P). Exact (pure exponent arithmetic, no mantissa change).
__device__ __forceinline__ float renorm_step(float v, int& sigma) {
  float m = wave_fmax_all(v);
  int e = ((__float_as_int(m) >> 23) & 0xff) - 127;
  sigma += e + 6;
  return v * __int_as_float((127 - e) << 23);
}

__device__ __forceinline__ int seq_len(const float* mb, int l) {
  float lenf = 0.f;
  for (int t = l; t < S_LEN; t += 64) lenf += mb[t];
  lenf = wave_sum(lenf);
  int len = (int)(lenf + 0.5f);
  if (len < 1) len = 1;
  if (len > S_LEN) len = S_LEN;
  return len;
}

// ---- chunk kernel: 4 wave-items per 256-thread block (occupancy fix).
// item = b*NSLOT + slot. slot<8 -> forward run of chunk k=slot (from alpha0
// for k==0, from ones otherwise) + chunk score partial; slot>=8 -> backward
// run of chunk k=slot-7 (from ones). Linear-space recursion with P/64 folded.
__global__ __launch_bounds__(256) void crf_chunk_kernel(
    const float* __restrict__ em, const int* __restrict__ tags,
    const float* __restrict__ mask, const float* __restrict__ trans,
    float* __restrict__ Vf, float* __restrict__ Vb,
    float* __restrict__ sf, float* __restrict__ sb,
    float* __restrict__ m0a, float* __restrict__ sca,
    int nitems)
{
  const int item = blockIdx.x * 4 + (threadIdx.x >> 6);
  if (item >= nitems) return;
  const int b = item / NSLOT;
  const int slot = item - b * NSLOT;
  const int l = threadIdx.x & 63;
  const float* emb = em + (size_t)b * S_LEN * LTAGS;
  const int len = seq_len(mask + (size_t)b * S_LEN, l);

  if (slot < NCHUNK) {
    const int k = slot;
    const int tstart = k * CHUNK + 1;
    const int tend = (k + 1) * CHUNK < len - 1 ? (k + 1) * CHUNK : len - 1;

    PMat P;  // column l of exp(T)/64: pair (P[2i][l], P[2i+1][l])
#pragma unroll
    for (int i = 0; i < 32; ++i)
      pmat_set(P, i, __expf(trans[(2 * i) * LTAGS + l]) * 0.015625f,
                     __expf(trans[(2 * i + 1) * LTAGS + l]) * 0.015625f);

    float v, m0 = 0.f; int sigma = 0;
    if (k == 0) {
      float a0 = trans[BOS_TAG * LTAGS + l] + emb[l];
      m0 = wave_fmax_all(a0);
      v = __expf(a0 - m0);
    } else {
      v = 1.f;
    }

    // gold-path score over this chunk's steps
    const int* tb = tags + (size_t)b * S_LEN;
    float sc = 0.f;
    for (int tt = tstart + l; tt <= tend; tt += 64) {
      int cur = tb[tt], prev = tb[tt - 1];
      sc += emb[(size_t)tt * LTAGS + cur] + trans[prev * LTAGS + cur];
    }
    sc = wave_sum(sc);
    if (k == 0) {
      int t0 = tb[0];
      sc += trans[BOS_TAG * LTAGS + t0] + emb[t0];
    }

    const float* ep = emb + (size_t)tstart * LTAGS + l;
    float eA = (tstart <= tend) ? ep[0] : 0.f;
    float eB = (tstart + 1 <= tend) ? ep[LTAGS] : 0.f;
    for (int t = tstart; t <= tend; ++t) {
      float eC = (t + 2 <= tend) ? ep[2 * LTAGS] : 0.f;
      ep += LTAGS;
      float E = __expf(eA);
      v = dot64(P, v) * E;
      v = renorm_step(v, sigma);
      eA = eB; eB = eC;
    }
    Vf[((size_t)b * NCHUNK + k) * LTAGS + l] = v;
    if (l == 0) {
      sf[b * NCHUNK + k] = (float)sigma;
      sca[b * NCHUNK + k] = sc;
      if (k == 0) m0a[b] = m0;
    }
  } else {
    const int k = slot - NCHUNK + 1; // 1..7
    const int tstart = k * CHUNK + 1;
    const int tend = (k + 1) * CHUNK < len - 1 ? (k + 1) * CHUNK : len - 1;

    PMat P;  // row l of exp(T)/64: pair (P[l][2i], P[l][2i+1])
#pragma unroll
    for (int i = 0; i < 32; ++i)
      pmat_set(P, i, __expf(trans[l * LTAGS + 2 * i]) * 0.015625f,
                     __expf(trans[l * LTAGS + 2 * i + 1]) * 0.015625f);

    float u = 1.f; int sigma = 0;
    const float* ep = emb + (size_t)tend * LTAGS + l;
    float eA = (tend >= tstart) ? ep[0] : 0.f;
    float eB = (tend - 1 >= tstart) ? ep[-LTAGS] : 0.f;
    for (int t = tend; t >= tstart; --t) {
      float eC = (t - 2 >= tstart) ? ep[-2 * LTAGS] : 0.f;
      ep -= LTAGS;
      float E = __expf(eA);
      float w = E * u;           // (E ⊙ u), then u' = P_row · w
      u = dot64(P, w);
      u = renorm_step(u, sigma);
      eA = eB; eB = eC;
    }
    Vb[((size_t)b * NCHUNK + k) * LTAGS + l] = u;
    if (l == 0) sb[b * NCHUNK + k] = (float)sigma;
  }
}

// ---- combine: rank-1 chunk stitching + score assembly, 4 batches/block.
__global__ __launch_bounds__(256) void crf_combine_kernel(
    const float* __restrict__ mask, const int* __restrict__ tags,
    const float* __restrict__ trans,
    const float* __restrict__ Vf, const float* __restrict__ Vb,
    const float* __restrict__ sf, const float* __restrict__ sb,
    const float* __restrict__ m0a, const float* __restrict__ sca,
    float* __restrict__ nll, int B)
{
  const int b = blockIdx.x * 4 + (threadIdx.x >> 6);
  if (b >= B) return;
  const int l = threadIdx.x & 63;
  const int len = seq_len(mask + (size_t)b * S_LEN, l);
  const int kb = (len >= 2) ? (len - 2) / CHUNK : 0;

  const float* vf = Vf + (size_t)b * NCHUNK * LTAGS;
  const float* vb = Vb + (size_t)b * NCHUNK * LTAGS;
  const float tvec = __expf(trans[l * LTAGS + EOS_TAG]);

  float vf0 = vf[l];
  float lp;
  if (kb == 0) {
    lp = m0a[b] + LN2F * sf[b * NCHUNK] + logf(wave_sum(vf0 * tvec));
  } else {
    lp = m0a[b] + LN2F * (sf[b * NCHUNK] + sb[b * NCHUNK + 1])
       + logf(wave_sum(vf0 * vb[1 * LTAGS + l]));
    for (int k = 1; k < kb; ++k) {
      float vfk = vf[(size_t)k * LTAGS + l];
      lp += LN2F * sb[b * NCHUNK + k + 1]
          + logf(wave_sum(vfk * vb[(size_t)(k + 1) * LTAGS + l]))
          - logf(wave_sum(vfk));
    }
    float vfb = vf[(size_t)kb * LTAGS + l];
    lp += logf(wave_sum(vfb * tvec)) - logf(wave_sum(vfb));
  }

  float sc = 0.f;
#pragma unroll
  for (int k = 0; k < NCHUNK; ++k) sc += sca[b * NCHUNK + k];
  const int* tb = tags + (size_t)b * S_LEN;
  sc += trans[tb[len - 1] * LTAGS + EOS_TAG];

  if (l == 0) nll[b] = lp - sc;
}

__global__ __launch_bounds__(64) void crf_reduce_kernel(
    const float* __restrict__ nll, float* __restrict__ out, int B) {
  float s = 0.f;
  for (int i = threadIdx.x; i < B; i += 64) s += nll[i];
  s = wave_sum(s);
  if (threadIdx.x == 0) out[0] = s; // sum(partition - score) == -sum(score - partition)
}

// ---- fallback: monolithic per-batch forward (linear space), used only if
// d_ws is too small for the chunked layout.
__global__ __launch_bounds__(64) void crf_mono_kernel(
    const float* __restrict__ em, const int* __restrict__ tags,
    const float* __restrict__ mask, const float* __restrict__ trans,
    float* __restrict__ partial)
{
  const int b = blockIdx.x;
  const int l = threadIdx.x;
  const float* emb = em + (size_t)b * S_LEN * LTAGS;
  const int len = seq_len(mask + (size_t)b * S_LEN, l);

  PMat P;
#pragma unroll
  for (int i = 0; i < 32; ++i)
    pmat_set(P, i, __expf(trans[(2 * i) * LTAGS + l]) * 0.015625f,
                   __expf(trans[(2 * i + 1) * LTAGS + l]) * 0.015625f);

  const int* tb = tags + (size_t)b * S_LEN;
  float sc = 0.f;
  for (int tt = 1 + l; tt <= len - 1; tt += 64) {
    int cur = tb[tt], prev = tb[tt - 1];
    sc += emb[(size_t)tt * LTAGS + cur] + trans[prev * LTAGS + cur];
  }
  sc = wave_sum(sc);
  int t0 = tb[0];
  sc += trans[BOS_TAG * LTAGS + t0] + emb[t0] + trans[tb[len - 1] * LTAGS + EOS_TAG];

  float a0 = trans[BOS_TAG * LTAGS + l] + emb[l];
  float m0 = wave_fmax_all(a0);
  float v = __expf(a0 - m0);
  int sigma = 0;
  for (int t = 1; t <= len - 1; ++t) {
    float E = __expf(emb[(size_t)t * LTAGS + l]);
    v = dot64(P, v) * E;
    v = renorm_step(v, sigma);
  }
  float tvec = __expf(trans[l * LTAGS + EOS_TAG]);
  float lp = m0 + LN2F * (float)sigma + logf(wave_sum(v * tvec));
  if (l == 0) partial[b] = lp - sc;
}

extern "C" void kernel_launch(void* const* d_in, const int* in_sizes, int n_in,
                              void* d_out, int out_size, void* d_ws, size_t ws_size,
                              hipStream_t stream) {
  const float* em = (const float*)d_in[0];
  const int* tags = (const int*)d_in[1];
  const float* mask = (const float*)d_in[2];
  const float* trans = (const float*)d_in[3];
  float* out = (float*)d_out;

  const int B = in_sizes[1] / S_LEN;

  const size_t nV = (size_t)B * NCHUNK * LTAGS;
  const size_t needFloats = 2 * nV + 3 * (size_t)B * NCHUNK + 2 * (size_t)B;
  if (ws_size >= needFloats * sizeof(float)) {
    float* Vf  = (float*)d_ws;
    float* Vb  = Vf + nV;
    float* sf  = Vb + nV;
    float* sb  = sf + (size_t)B * NCHUNK;
    float* sca = sb + (size_t)B * NCHUNK;
    float* m0a = sca + (size_t)B * NCHUNK;
    float* nll = m0a + B;

    const int nitems = B * NSLOT;
    crf_chunk_kernel<<<(nitems + 3) / 4, 256, 0, stream>>>(
        em, tags, mask, trans, Vf, Vb, sf, sb, m0a, sca, nitems);
    crf_combine_kernel<<<(B + 3) / 4, 256, 0, stream>>>(
        mask, tags, trans, Vf, Vb, sf, sb, m0a, sca, nll, B);
    crf_reduce_kernel<<<1, 64, 0, stream>>>(nll, out, B);
  } else {
    float* partial = (float*)d_ws;
    crf_mono_kernel<<<B, 64, 0, stream>>>(em, tags, mask, trans, partial);
    crf_reduce_kernel<<<1, 64, 0, stream>>>(partial, out, B);
  }
}

// Round 6
// 97.586 us; speedup vs baseline: 2.2162x; 2.2162x over previous
//
#include <hip/hip_runtime.h>
#include <math.h>

#define BOS_TAG 62
#define EOS_TAG 63
#define S_LEN   1024
#define NCH     32
#define CH      32          // S_LEN / NCH
#define WPB     2           // NCH/16: fwd waves per batch (same for bwd)
#define LN2F    0.69314718055994530942f

typedef short  short8 __attribute__((ext_vector_type(8)));
typedef float  f32x4  __attribute__((ext_vector_type(4)));

template <int CTRL>
__device__ __forceinline__ int dpp_mov(int v) {
  return __builtin_amdgcn_update_dpp(v, v, CTRL, 0xf, 0xf, false);
}
template <int CTRL>
__device__ __forceinline__ float dpp_fmax_step(float v) {
  return fmaxf(v, __int_as_float(dpp_mov<CTRL>(__float_as_int(v))));
}
__device__ __forceinline__ float wave_fmax_all(float v) {
  v = dpp_fmax_step<0x111>(v); v = dpp_fmax_step<0x112>(v);
  v = dpp_fmax_step<0x114>(v); v = dpp_fmax_step<0x118>(v);
  v = dpp_fmax_step<0x142>(v); v = dpp_fmax_step<0x143>(v);
  return __int_as_float(__builtin_amdgcn_readlane(__float_as_int(v), 63));
}
__device__ __forceinline__ float wave_sum(float v) {
#pragma unroll
  for (int off = 32; off; off >>= 1) v += __shfl_xor(v, off, 64);
  return v;
}
__device__ __forceinline__ unsigned short f2bf(float v) {   // round-half-up (positive vals)
  return (unsigned short)((__float_as_uint(v) + 0x8000u) >> 16);
}
__device__ __forceinline__ float bf2f(unsigned short u) {
  return __uint_as_float(((unsigned)u) << 16);
}
__device__ __forceinline__ int seq_len64(const float* mb, int l) {
  float lenf = 0.f;
  for (int t = l; t < S_LEN; t += 64) lenf += mb[t];
  lenf = wave_sum(lenf);
  int len = (int)(lenf + 0.5f);
  return max(1, min(S_LEN, len));
}

// ===== MFMA chunk kernel: 16 chains (rows) per wave, V in per-wave LDS =====
// wave w: dir = w&1 (0 fwd / 1 bwd), idx = w>>1, b = idx/WPB, half = idx%WPB.
// Row r <-> chunk kg = half*16 + r. Fwd: V <- (V x P) .* E_t. Bwd: V <- (V .* E_t) x P^T.
__global__ __launch_bounds__(256) void crf_chunk_mfma(
    const float* __restrict__ em, const int* __restrict__ tags,
    const float* __restrict__ mask, const float* __restrict__ trans,
    unsigned short* __restrict__ Vf, unsigned short* __restrict__ Vb,
    float* __restrict__ sf, float* __restrict__ sb,
    float* __restrict__ sca, float* __restrict__ m0a, int B)
{
  __shared__ unsigned short smem[4][16 * 64];
  const int wv = threadIdx.x >> 6;
  const int l  = threadIdx.x & 63;
  const int w  = blockIdx.x * 4 + wv;
  const int nwaves = 2 * B * WPB;
  if (w >= nwaves) return;
  const int dir  = w & 1;
  const int idx  = w >> 1;
  const int b    = idx / WPB;
  const int half = idx % WPB;
  unsigned short* smw = smem[wv];
  const float* embase = em + (size_t)b * S_LEN * 64;
  const int g = l >> 4, c = l & 15;

  const int len = seq_len64(mask + (size_t)b * S_LEN, l);

  // ---- B fragments: bf16 exp(trans). fwd B[k][col]=P[k][col]; bwd =P[col][k].
  short8 Bf[2][4];
#pragma unroll
  for (int kc = 0; kc < 2; ++kc)
#pragma unroll
    for (int n = 0; n < 4; ++n) {
      short8 f;
#pragma unroll
      for (int j = 0; j < 8; ++j) {
        int k = kc * 32 + g * 8 + j, col = n * 16 + c;
        float tv = dir ? trans[col * 64 + k] : trans[k * 64 + col];
        f[j] = (short)f2bf(__expf(tv));
      }
      Bf[kc][n] = f;
    }

  // ---- init V rows (swizzled LDS [16][64] bf16) ----
#pragma unroll
  for (int r = 0; r < 16; ++r) {
    float v = 1.0f;
    if (dir == 0 && half == 0 && r == 0) {
      float a0 = trans[BOS_TAG * 64 + l] + embase[l];
      float m0 = wave_fmax_all(a0);
      v = __expf(a0 - m0);
      if (l == 0) m0a[b] = m0;
    }
    smw[(r * 64 + l) ^ ((r & 7) << 3)] = f2bf(v);
  }

  // ---- per-row step counts; pre-save empty rows; find the partial row ----
  unsigned short* Vout = dir ? Vb : Vf;
  float* sout = dir ? sb : sf;
  int fstep[16];
  int ps = -1, pr = -1;
#pragma unroll
  for (int r = 0; r < 16; ++r) {
    int kg = half * 16 + r;
    int tend = min((kg + 1) * CH, len - 1);
    fstep[r] = tend - (kg * CH + 1);
    if (fstep[r] < 0) {
      Vout[((size_t)b * NCH + kg) * 64 + l] = 0x3F80; // bf16 1.0
      if (l == 0) sout[b * NCH + kg] = 0.f;
    }
    if (fstep[r] >= 0 && fstep[r] < CH - 1) { ps = fstep[r]; pr = r; }
  }

  const int byteA0 = (c * 128 + g * 16) ^ ((c & 7) << 4);
  const int byteA1 = (c * 128 + 64 + g * 16) ^ ((c & 7) << 4);
  int sigma = 0;

  auto renorm16 = [&](float* d) {
    float m = d[0];
#pragma unroll
    for (int i = 1; i < 16; ++i) m = fmaxf(m, d[i]);
    m = wave_fmax_all(m);
    int e = ((__float_as_int(m) >> 23) & 0xff) - 127;
    float s = __int_as_float((127 - e) << 23);
#pragma unroll
    for (int i = 0; i < 16; ++i) d[i] *= s;
    sigma += e;
  };
  auto save_row = [&](int r) {
    unsigned short v = smw[(r * 64 + l) ^ ((r & 7) << 3)];
    int kg = half * 16 + r;
    Vout[((size_t)b * NCH + kg) * 64 + l] = v;
    if (l == 0) sout[b * NCH + kg] = (float)sigma;
  };

  if (dir == 0) {
    // ---- gold-path score partial over this wave's t-range ----
    {
      const int* tb = tags + (size_t)b * S_LEN;
      int lo = half * (16 * CH) + 1;
      int hi = min(half * (16 * CH) + 16 * CH, len - 1);
      float sc = 0.f;
      for (int t = lo + l; t <= hi; t += 64)
        sc += embase[(size_t)t * 64 + tb[t]] + trans[tb[t - 1] * 64 + tb[t]];
      sc = wave_sum(sc);
      if (half == 0) sc += trans[BOS_TAG * 64 + tb[0]] + embase[tb[0]];
      if (l == 0) sca[b * WPB + half] = sc;
    }

    int tb0[4];
#pragma unroll
    for (int reg = 0; reg < 4; ++reg) tb0[reg] = (half * 16 + g * 4 + reg) * CH + 1;

    auto loadF = [&](float* e, int tl) {
#pragma unroll
      for (int reg = 0; reg < 4; ++reg) {
        int tr = min(tb0[reg] + tl, S_LEN - 1);
        const float* rowp = embase + (size_t)tr * 64;
#pragma unroll
        for (int n = 0; n < 4; ++n) e[reg * 4 + n] = rowp[n * 16 + c];
      }
    };
    auto bodyF = [&](const float* e, int tl) {
      short8 a0 = *reinterpret_cast<const short8*>((const char*)smw + byteA0);
      short8 a1 = *reinterpret_cast<const short8*>((const char*)smw + byteA1);
      f32x4 acc[4];
#pragma unroll
      for (int n = 0; n < 4; ++n) {
        f32x4 z = {0.f, 0.f, 0.f, 0.f};
        z = __builtin_amdgcn_mfma_f32_16x16x32_bf16(a0, Bf[0][n], z, 0, 0, 0);
        acc[n] = __builtin_amdgcn_mfma_f32_16x16x32_bf16(a1, Bf[1][n], z, 0, 0, 0);
      }
      float d[16];
#pragma unroll
      for (int reg = 0; reg < 4; ++reg)
#pragma unroll
        for (int n = 0; n < 4; ++n)
          d[reg * 4 + n] = acc[n][reg] * __expf(e[reg * 4 + n]);
      if ((tl & 3) == 3 || tl == CH - 1) renorm16(d);
#pragma unroll
      for (int reg = 0; reg < 4; ++reg)
#pragma unroll
        for (int n = 0; n < 4; ++n) {
          int row = g * 4 + reg, col = n * 16 + c;
          smw[(row * 64 + col) ^ ((row & 7) << 3)] = f2bf(d[reg * 4 + n]);
        }
      if (tl == ps) save_row(pr);
    };

    float eA[16], eB2[16];
    loadF(eA, 0);
    for (int tl = 0; tl < CH; tl += 2) {
      loadF(eB2, tl + 1);
      bodyF(eA, tl);
      if (tl + 2 < CH) loadF(eA, tl + 2);
      bodyF(eB2, tl + 1);
    }
#pragma unroll
    for (int r = 0; r < 16; ++r)
      if (fstep[r] == CH - 1) save_row(r);
  } else {
    // ---- bwd: chain for A rows is rc = l&15 = c ----
    const int tendl = min((half * 16 + c + 1) * CH, len - 1);

    auto loadB = [&](float* e, int tl) {
      int tr = tendl - tl;
      const float* rowp = embase + (size_t)tr * 64;
      float4 q0 = *reinterpret_cast<const float4*>(rowp + g * 8);
      float4 q1 = *reinterpret_cast<const float4*>(rowp + g * 8 + 4);
      float4 q2 = *reinterpret_cast<const float4*>(rowp + 32 + g * 8);
      float4 q3 = *reinterpret_cast<const float4*>(rowp + 32 + g * 8 + 4);
      e[0] = q0.x; e[1] = q0.y; e[2] = q0.z; e[3] = q0.w;
      e[4] = q1.x; e[5] = q1.y; e[6] = q1.z; e[7] = q1.w;
      e[8] = q2.x; e[9] = q2.y; e[10] = q2.z; e[11] = q2.w;
      e[12] = q3.x; e[13] = q3.y; e[14] = q3.z; e[15] = q3.w;
    };
    auto bodyB = [&](const float* e, int tl) {
      short8 ar0 = *reinterpret_cast<const short8*>((const char*)smw + byteA0);
      short8 ar1 = *reinterpret_cast<const short8*>((const char*)smw + byteA1);
      short8 a0, a1;
#pragma unroll
      for (int j = 0; j < 8; ++j) {
        float w0 = bf2f((unsigned short)ar0[j]) * __expf(e[j]);
        float w1 = bf2f((unsigned short)ar1[j]) * __expf(e[8 + j]);
        a0[j] = (short)f2bf(w0);
        a1[j] = (short)f2bf(w1);
      }
      f32x4 acc[4];
#pragma unroll
      for (int n = 0; n < 4; ++n) {
        f32x4 z = {0.f, 0.f, 0.f, 0.f};
        z = __builtin_amdgcn_mfma_f32_16x16x32_bf16(a0, Bf[0][n], z, 0, 0, 0);
        acc[n] = __builtin_amdgcn_mfma_f32_16x16x32_bf16(a1, Bf[1][n], z, 0, 0, 0);
      }
      float d[16];
#pragma unroll
      for (int reg = 0; reg < 4; ++reg)
#pragma unroll
        for (int n = 0; n < 4; ++n) d[reg * 4 + n] = acc[n][reg];
      if ((tl & 3) == 3 || tl == CH - 1) renorm16(d);
#pragma unroll
      for (int reg = 0; reg < 4; ++reg)
#pragma unroll
        for (int n = 0; n < 4; ++n) {
          int row = g * 4 + reg, col = n * 16 + c;
          smw[(row * 64 + col) ^ ((row & 7) << 3)] = f2bf(d[reg * 4 + n]);
        }
      if (tl == ps) save_row(pr);
    };

    float eA[16], eB2[16];
    loadB(eA, 0);
    for (int tl = 0; tl < CH; tl += 2) {
      loadB(eB2, tl + 1);
      bodyB(eA, tl);
      if (tl + 2 < CH) loadB(eA, tl + 2);
      bodyB(eB2, tl + 1);
    }
#pragma unroll
    for (int r = 0; r < 16; ++r)
      if (fstep[r] == CH - 1) save_row(r);
  }
}

// ===== combine: rank-1 chunk stitching + score assembly =====
__global__ __launch_bounds__(256) void crf_combine(
    const float* __restrict__ mask, const int* __restrict__ tags,
    const float* __restrict__ trans,
    const unsigned short* __restrict__ Vf, const unsigned short* __restrict__ Vb,
    const float* __restrict__ sf, const float* __restrict__ sb,
    const float* __restrict__ sca, const float* __restrict__ m0a,
    float* __restrict__ nll, int B)
{
  const int b = blockIdx.x * 4 + (threadIdx.x >> 6);
  if (b >= B) return;
  const int l = threadIdx.x & 63;
  const int len = seq_len64(mask + (size_t)b * S_LEN, l);
  const int kb = (len >= 2) ? (len - 2) / CH : 0;

  const unsigned short* vf = Vf + (size_t)b * NCH * 64;
  const unsigned short* vb = Vb + (size_t)b * NCH * 64;
  const float tvec = __expf(trans[l * 64 + EOS_TAG]);

  float vf0 = bf2f(vf[l]);
  float lp;
  if (kb == 0) {
    lp = m0a[b] + LN2F * sf[b * NCH] + logf(wave_sum(vf0 * tvec));
  } else {
    lp = m0a[b] + LN2F * (sf[b * NCH] + sb[b * NCH + 1])
       + logf(wave_sum(vf0 * bf2f(vb[1 * 64 + l])));
    for (int k = 1; k < kb; ++k) {
      float vfk = bf2f(vf[(size_t)k * 64 + l]);
      lp += LN2F * sb[b * NCH + k + 1]
          + logf(wave_sum(vfk * bf2f(vb[(size_t)(k + 1) * 64 + l])))
          - logf(wave_sum(vfk));
    }
    float vfb = bf2f(vf[(size_t)kb * 64 + l]);
    lp += logf(wave_sum(vfb * tvec)) - logf(wave_sum(vfb));
  }

  float sc = 0.f;
#pragma unroll
  for (int h = 0; h < WPB; ++h) sc += sca[b * WPB + h];
  const int* tb = tags + (size_t)b * S_LEN;
  sc += trans[tb[len - 1] * 64 + EOS_TAG];

  if (l == 0) nll[b] = lp - sc;
}

__global__ __launch_bounds__(64) void crf_reduce(
    const float* __restrict__ nll, float* __restrict__ out, int B) {
  float s = 0.f;
  for (int i = threadIdx.x; i < B; i += 64) s += nll[i];
  s = wave_sum(s);
  if (threadIdx.x == 0) out[0] = s;
}

// ===== fallback: monolithic per-batch forward (VALU, linear space) =====
__global__ __launch_bounds__(64) void crf_mono(
    const float* __restrict__ em, const int* __restrict__ tags,
    const float* __restrict__ mask, const float* __restrict__ trans,
    float* __restrict__ partial)
{
  const int b = blockIdx.x;
  const int l = threadIdx.x;
  const float* emb = em + (size_t)b * S_LEN * 64;
  const int len = seq_len64(mask + (size_t)b * S_LEN, l);

  float p[64];
#pragma unroll
  for (int i = 0; i < 64; ++i) p[i] = __expf(trans[i * 64 + l]) * 0.015625f;

  const int* tb = tags + (size_t)b * S_LEN;
  float sc = 0.f;
  for (int tt = 1 + l; tt <= len - 1; tt += 64)
    sc += emb[(size_t)tt * 64 + tb[tt]] + trans[tb[tt - 1] * 64 + tb[tt]];
  sc = wave_sum(sc);
  sc += trans[BOS_TAG * 64 + tb[0]] + emb[tb[0]] + trans[tb[len - 1] * 64 + EOS_TAG];

  float a0 = trans[BOS_TAG * 64 + l] + emb[l];
  float m0 = wave_fmax_all(a0);
  float v = __expf(a0 - m0);
  int sigma = 0;
  for (int t = 1; t <= len - 1; ++t) {
    float E = __expf(emb[(size_t)t * 64 + l]);
    int xi = __float_as_int(v);
    float s0 = 0.f, s1 = 0.f, s2 = 0.f, s3 = 0.f;
#pragma unroll
    for (int i = 0; i < 64; i += 4) {
      s0 = fmaf(__int_as_float(__builtin_amdgcn_readlane(xi, i + 0)), p[i + 0], s0);
      s1 = fmaf(__int_as_float(__builtin_amdgcn_readlane(xi, i + 1)), p[i + 1], s1);
      s2 = fmaf(__int_as_float(__builtin_amdgcn_readlane(xi, i + 2)), p[i + 2], s2);
      s3 = fmaf(__int_as_float(__builtin_amdgcn_readlane(xi, i + 3)), p[i + 3], s3);
    }
    v = ((s0 + s1) + (s2 + s3)) * E;
    float m = wave_fmax_all(v);
    int e = ((__float_as_int(m) >> 23) & 0xff) - 127;
    sigma += e + 6;
    v *= __int_as_float((127 - e) << 23);
  }
  float tvec = __expf(trans[l * 64 + EOS_TAG]);
  float lp = m0 + LN2F * (float)sigma + logf(wave_sum(v * tvec));
  if (l == 0) partial[b] = lp - sc;
}

extern "C" void kernel_launch(void* const* d_in, const int* in_sizes, int n_in,
                              void* d_out, int out_size, void* d_ws, size_t ws_size,
                              hipStream_t stream) {
  const float* em = (const float*)d_in[0];
  const int* tags = (const int*)d_in[1];
  const float* mask = (const float*)d_in[2];
  const float* trans = (const float*)d_in[3];
  float* out = (float*)d_out;

  const int B = in_sizes[1] / S_LEN;

  // layout: floats [sf | sb | sca | m0a | nll], then ushort [Vf | Vb]
  const size_t nSig = (size_t)B * NCH;
  const size_t nFlt = 2 * nSig + (size_t)B * WPB + 2 * (size_t)B;
  const size_t nV   = (size_t)B * NCH * 64;
  const size_t need = nFlt * sizeof(float) + 2 * nV * sizeof(unsigned short);

  if (ws_size >= need) {
    float* sf  = (float*)d_ws;
    float* sb  = sf + nSig;
    float* sca = sb + nSig;
    float* m0a = sca + (size_t)B * WPB;
    float* nll = m0a + B;
    unsigned short* Vf = (unsigned short*)(nll + B);
    unsigned short* Vb = Vf + nV;

    const int nwaves = 2 * B * WPB;
    crf_chunk_mfma<<<(nwaves + 3) / 4, 256, 0, stream>>>(
        em, tags, mask, trans, Vf, Vb, sf, sb, sca, m0a, B);
    crf_combine<<<(B + 3) / 4, 256, 0, stream>>>(
        mask, tags, trans, Vf, Vb, sf, sb, sca, m0a, nll, B);
    crf_reduce<<<1, 64, 0, stream>>>(nll, out, B);
  } else {
    float* partial = (float*)d_ws;
    crf_mono<<<B, 64, 0, stream>>>(em, tags, mask, trans, partial);
    crf_reduce<<<1, 64, 0, stream>>>(partial, out, B);
  }
}